// Round 1
// baseline (724.837 us; speedup 1.0000x reference)
//
#include <hip/hip_runtime.h>
#include <hip/hip_fp16.h>
#include <stdint.h>

#define B_ROWS 65536
#define K_DIM 3072
#define N_DIM 1024

#define BM 128
#define BN 256
#define BK 64
#define NBLK 4            // N_DIM / BN
#define THREADS 512
#define KSTEPS (K_DIM / BK)   // 48
#define LDP 72            // LDS leading dim: 64 + 8 f16 pad (keeps 16B alignment, kills 16-way conflicts)

#define MARGIN 6.0e-3f

typedef _Float16 f16x8 __attribute__((ext_vector_type(8)));
typedef _Float16 f16x4 __attribute__((ext_vector_type(4)));
typedef float f32x4 __attribute__((ext_vector_type(4)));

__device__ __forceinline__ float gelu_exact(float v) {
  return 0.5f * v * (1.0f + erff(v * 0.7071067811865476f));
}

// ---------------- kernel 1: w1 [K][N] fp32 -> w1t [N][K] fp16 ----------------
__global__ void k_w1t(const float* __restrict__ w1, _Float16* __restrict__ w1t) {
  __shared__ float tile[32][33];
  const int kb = blockIdx.x, nb = blockIdx.y;
  const int c = threadIdx.x & 31, r8 = threadIdx.x >> 5;
#pragma unroll
  for (int i = 0; i < 4; ++i) {
    const int r = r8 + i * 8;
    tile[r][c] = w1[(size_t)(kb * 32 + r) * N_DIM + nb * 32 + c];
  }
  __syncthreads();
#pragma unroll
  for (int i = 0; i < 4; ++i) {
    const int r = r8 + i * 8;
    w1t[(size_t)(nb * 32 + r) * K_DIM + kb * 32 + c] = (_Float16)tile[c][r];
  }
}

// ---------------- kernel 2: main fp16 MFMA GEMM + fused gelu/W2 epilogue -----
__global__ __launch_bounds__(THREADS) void k_gemm(
    const float* __restrict__ x, const _Float16* __restrict__ w1t,
    const float* __restrict__ b1, const float* __restrict__ w2,
    float* __restrict__ partial) {
  __shared__ __align__(16) _Float16 As[BM][LDP];
  __shared__ __align__(16) _Float16 Bs[BN][LDP];
  __shared__ float pl[BM][NBLK][3];

  const int t = threadIdx.x;
  const int lane = t & 63;
  const int wid = t >> 6;
  const int wr = wid >> 2;   // 0..1  (row half of 128)
  const int wc = wid & 3;    // 0..3  (col quarter of 256)
  const int l15 = lane & 15;
  const int lhi = lane >> 4;

  const int bid = blockIdx.x;
  const int nb = bid & (NBLK - 1);   // n-block fastest -> per-XCD w1t panel reuse
  const int rb = bid >> 2;
  const int row0 = rb * BM;
  const int n0 = nb * BN;

  f32x4 acc[4][4];
#pragma unroll
  for (int m = 0; m < 4; ++m)
#pragma unroll
    for (int n = 0; n < 4; ++n) acc[m][n] = (f32x4){0.f, 0.f, 0.f, 0.f};

  for (int kt = 0; kt < KSTEPS; ++kt) {
    const int k0 = kt * BK;
    float4 av[4];
    f16x8 bv[4];
#pragma unroll
    for (int i = 0; i < 4; ++i) {        // A: 128x64 fp32 = 2048 float4
      const int idx = i * THREADS + t;
      const int ar = idx >> 4, ac = (idx & 15) << 2;
      av[i] = *(const float4*)(x + (size_t)(row0 + ar) * K_DIM + k0 + ac);
    }
#pragma unroll
    for (int i = 0; i < 4; ++i) {        // B: 256x64 f16 = 2048 f16x8
      const int idx = i * THREADS + t;
      const int br = idx >> 3, bc = (idx & 7) << 3;
      bv[i] = *(const f16x8*)(w1t + (size_t)(n0 + br) * K_DIM + k0 + bc);
    }
    __syncthreads();   // previous tile fully consumed
#pragma unroll
    for (int i = 0; i < 4; ++i) {
      const int idx = i * THREADS + t;
      const int ar = idx >> 4, ac = (idx & 15) << 2;
      f16x4 hv = {(_Float16)av[i].x, (_Float16)av[i].y, (_Float16)av[i].z, (_Float16)av[i].w};
      *(f16x4*)&As[ar][ac] = hv;
    }
#pragma unroll
    for (int i = 0; i < 4; ++i) {
      const int idx = i * THREADS + t;
      const int br = idx >> 3, bc = (idx & 7) << 3;
      *(f16x8*)&Bs[br][bc] = bv[i];
    }
    __syncthreads();
#pragma unroll
    for (int kk = 0; kk < BK; kk += 32) {
      f16x8 a[4], b[4];
#pragma unroll
      for (int m = 0; m < 4; ++m)
        a[m] = *(const f16x8*)&As[wr * 64 + m * 16 + l15][kk + lhi * 8];
#pragma unroll
      for (int n = 0; n < 4; ++n)
        b[n] = *(const f16x8*)&Bs[wc * 64 + n * 16 + l15][kk + lhi * 8];
#pragma unroll
      for (int m = 0; m < 4; ++m)
#pragma unroll
        for (int n = 0; n < 4; ++n)
          acc[m][n] = __builtin_amdgcn_mfma_f32_16x16x32_f16(a[m], b[n], acc[m][n], 0, 0, 0);
    }
  }

  // epilogue: h -> gelu -> *W2 -> per-row partial logits (3) for this n-block
  float w2v[4][3], b1v[4];
#pragma unroll
  for (int n = 0; n < 4; ++n) {
    const int gc = n0 + wc * 64 + n * 16 + l15;
    b1v[n] = b1[gc];
    w2v[n][0] = w2[gc * 3 + 0];
    w2v[n][1] = w2[gc * 3 + 1];
    w2v[n][2] = w2[gc * 3 + 2];
  }
#pragma unroll
  for (int m = 0; m < 4; ++m) {
#pragma unroll
    for (int j = 0; j < 4; ++j) {
      float s0 = 0.f, s1 = 0.f, s2 = 0.f;
#pragma unroll
      for (int n = 0; n < 4; ++n) {
        const float v = acc[m][n][j] + b1v[n];
        const float g = gelu_exact(v);
        s0 += g * w2v[n][0];
        s1 += g * w2v[n][1];
        s2 += g * w2v[n][2];
      }
#pragma unroll
      for (int off = 1; off < 16; off <<= 1) {   // reduce across the 16 col-lanes
        s0 += __shfl_xor(s0, off, 64);
        s1 += __shfl_xor(s1, off, 64);
        s2 += __shfl_xor(s2, off, 64);
      }
      if (l15 == 0) {
        const int r = wr * 64 + m * 16 + lhi * 4 + j;
        pl[r][wc][0] = s0;
        pl[r][wc][1] = s1;
        pl[r][wc][2] = s2;
      }
    }
  }
  __syncthreads();
  if (t < BM) {
#pragma unroll
    for (int e = 0; e < 3; ++e) {
      const float s = pl[t][0][e] + pl[t][1][e] + pl[t][2][e] + pl[t][3][e];
      partial[(size_t)(row0 + t) * (NBLK * 3) + nb * 3 + e] = s;
    }
  }
}

// ---------------- shared finalize: softmax + top-k mask + renorm -------------
__device__ __forceinline__ void gate_store(float* __restrict__ out, int r,
                                           float l0, float l1, float l2, int kk) {
  const float mx = fmaxf(l0, fmaxf(l1, l2));
  const float e0 = expf(l0 - mx), e1 = expf(l1 - mx), e2 = expf(l2 - mx);
  const float s = e0 + e1 + e2;
  const float g0 = e0 / s, g1 = e1 / s, g2 = e2 / s;
  // rank with lax.top_k tie rule (ties -> lower index wins)
  const int r0 = (g1 > g0) + (g2 > g0);
  const int r1 = (g0 >= g1) + (g2 > g1);
  const int r2 = (g0 >= g2) + (g1 >= g2);
  const float m0 = (r0 < kk) ? 1.f : 0.f;
  const float m1 = (r1 < kk) ? 1.f : 0.f;
  const float m2 = (r2 < kk) ? 1.f : 0.f;
  const float ks = g0 * m0 + g1 * m1 + g2 * m2;
  const float inv = 1.f / (ks + 1e-8f);
  float* go = out + (size_t)r * 3;
  go[0] = g0 * m0 * inv;
  go[1] = g1 * m1 * inv;
  go[2] = g2 * m2 * inv;
  float* mo = out + (size_t)B_ROWS * 3 + (size_t)r * 3;
  mo[0] = m0;
  mo[1] = m1;
  mo[2] = m2;
}

// ---------------- kernel 3: logits -> outputs + fallback detect --------------
__global__ void k_gate(const float* __restrict__ partial, const float* __restrict__ b2,
                       const int* __restrict__ kp, float* __restrict__ out,
                       int* __restrict__ fb_cnt, int* __restrict__ fb_rows) {
  const int r = blockIdx.x * blockDim.x + threadIdx.x;
  if (r >= B_ROWS) return;
  const float* p = partial + (size_t)r * (NBLK * 3);
  float l0 = b2[0], l1 = b2[1], l2 = b2[2];
#pragma unroll
  for (int c = 0; c < NBLK; ++c) {
    l0 += p[c * 3 + 0];
    l1 += p[c * 3 + 1];
    l2 += p[c * 3 + 2];
  }
  int kk = *kp;
  kk = kk < 3 ? kk : 3;
  gate_store(out, r, l0, l1, l2, kk);
  const float mx = fmaxf(l0, fmaxf(l1, l2));
  const float mn = fminf(l0, fminf(l1, l2));
  const float mid = l0 + l1 + l2 - mx - mn;
  float gap = 1e30f;
  if (kk == 1) gap = mx - mid;
  else if (kk == 2) gap = mid - mn;
  if (gap < MARGIN) {
    const int i = atomicAdd(fb_cnt, 1);
    fb_rows[i] = r;
  }
}

// ---------------- kernel 4: fp32 exact recompute of near-tie rows ------------
__global__ __launch_bounds__(256) void k_fb_gemm(
    const float* __restrict__ x, const float* __restrict__ w1,
    const float* __restrict__ b1, const float* __restrict__ w2,
    const int* __restrict__ fb_cnt, const int* __restrict__ fb_rows,
    float* __restrict__ fb_partial) {
  const int count = *fb_cnt;
  if (count == 0) return;
  const int nc = blockIdx.y;        // 16 chunks of 64 cols
  const int n0 = nc * 64;
  const int t = threadIdx.x;
  const int col = t & 63;
  const int wrow = t >> 6;          // wave id = row group of 4
  __shared__ float Xs[16][64];
  __shared__ float Ws[64][64];
  for (int slot = blockIdx.x; slot * 16 < count; slot += gridDim.x) {
    float accr[4] = {0.f, 0.f, 0.f, 0.f};
    for (int kt = 0; kt < K_DIM / 64; ++kt) {
      const int k0 = kt * 64;
      __syncthreads();
      {
        const int rr = t >> 4, c4 = (t & 15) << 2;
        int gi = slot * 16 + rr;
        gi = gi < count ? gi : count - 1;
        const int ridx = fb_rows[gi];
        *(float4*)&Xs[rr][c4] = *(const float4*)(x + (size_t)ridx * K_DIM + k0 + c4);
      }
#pragma unroll
      for (int i = 0; i < 4; ++i) {
        const int rr = i * 16 + (t >> 4), c4 = (t & 15) << 2;
        *(float4*)&Ws[rr][c4] = *(const float4*)(w1 + (size_t)(k0 + rr) * N_DIM + n0 + c4);
      }
      __syncthreads();
#pragma unroll 8
      for (int kkk = 0; kkk < 64; ++kkk) {
        const float wv = Ws[kkk][col];
#pragma unroll
        for (int rr2 = 0; rr2 < 4; ++rr2) accr[rr2] += Xs[wrow * 4 + rr2][kkk] * wv;
      }
    }
    const float bvv = b1[n0 + col];
    const float w20 = w2[(n0 + col) * 3 + 0];
    const float w21 = w2[(n0 + col) * 3 + 1];
    const float w22 = w2[(n0 + col) * 3 + 2];
#pragma unroll
    for (int rr2 = 0; rr2 < 4; ++rr2) {
      const float v = accr[rr2] + bvv;
      const float g = gelu_exact(v);
      float c0 = g * w20, c1 = g * w21, c2 = g * w22;
#pragma unroll
      for (int off = 1; off < 64; off <<= 1) {
        c0 += __shfl_xor(c0, off, 64);
        c1 += __shfl_xor(c1, off, 64);
        c2 += __shfl_xor(c2, off, 64);
      }
      const int gi = slot * 16 + wrow * 4 + rr2;
      if (col == 0 && gi < count) {
        float* fp = fb_partial + ((size_t)gi * 16 + nc) * 3;
        fp[0] = c0;
        fp[1] = c1;
        fp[2] = c2;
      }
    }
  }
}

// ---------------- kernel 5: finalize fallback rows ---------------------------
__global__ void k_fb_fin(const float* __restrict__ fb_partial, const float* __restrict__ b2,
                         const int* __restrict__ kp, const int* __restrict__ fb_cnt,
                         const int* __restrict__ fb_rows, float* __restrict__ out) {
  const int i = blockIdx.x * blockDim.x + threadIdx.x;
  if (i >= *fb_cnt) return;
  const int r = fb_rows[i];
  float l0 = b2[0], l1 = b2[1], l2 = b2[2];
  const float* fp = fb_partial + (size_t)i * 48;
#pragma unroll
  for (int c = 0; c < 16; ++c) {
    l0 += fp[c * 3 + 0];
    l1 += fp[c * 3 + 1];
    l2 += fp[c * 3 + 2];
  }
  int kk = *kp;
  kk = kk < 3 ? kk : 3;
  gate_store(out, r, l0, l1, l2, kk);
}

extern "C" void kernel_launch(void* const* d_in, const int* in_sizes, int n_in,
                              void* d_out, int out_size, void* d_ws, size_t ws_size,
                              hipStream_t stream) {
  (void)in_sizes; (void)n_in; (void)out_size; (void)ws_size;
  const float* x  = (const float*)d_in[0];
  const float* w1 = (const float*)d_in[1];
  const float* b1 = (const float*)d_in[2];
  const float* w2 = (const float*)d_in[3];
  const float* b2 = (const float*)d_in[4];
  const int*   kp = (const int*)d_in[5];
  float* out = (float*)d_out;

  uint8_t* ws = (uint8_t*)d_ws;
  _Float16* w1t     = (_Float16*)(ws);            // 6,291,456 B
  float* partial    = (float*)(ws + 6291456);     // 3,145,728 B
  int* fb_cnt       = (int*)(ws + 9437184);       // 256 B (padded)
  int* fb_rows      = (int*)(ws + 9437440);       // 262,144 B
  float* fb_partial = (float*)(ws + 9699584);     // 12,582,912 B  (total ~21.3 MB)

  hipMemsetAsync(fb_cnt, 0, sizeof(int), stream);
  k_w1t<<<dim3(K_DIM / 32, N_DIM / 32), 256, 0, stream>>>(w1, w1t);
  k_gemm<<<dim3((B_ROWS / BM) * NBLK), THREADS, 0, stream>>>(x, w1t, b1, w2, partial);
  k_gate<<<dim3(B_ROWS / 256), 256, 0, stream>>>(partial, b2, kp, out, fb_cnt, fb_rows);
  k_fb_gemm<<<dim3(32, 16), 256, 0, stream>>>(x, w1, b1, w2, fb_cnt, fb_rows, fb_partial);
  k_fb_fin<<<dim3(B_ROWS / 256), 256, 0, stream>>>(fb_partial, b2, kp, fb_cnt, fb_rows, out);
}